// Round 9
// baseline (1212.623 us; speedup 1.0000x reference)
//
#include <hip/hip_runtime.h>
#include <hip/hip_fp16.h>

#define B_SZ 4
#define T_SEQ 2048
#define NH 16
#define HD 64
#define DMODEL 1024
#define MTOT (B_SZ * T_SEQ)   // 8192

typedef __bf16 bf16x8 __attribute__((ext_vector_type(8)));
typedef float f32x4 __attribute__((ext_vector_type(4)));
typedef float f32x2 __attribute__((ext_vector_type(2)));
typedef _Float16 f16x4 __attribute__((ext_vector_type(4)));
typedef _Float16 f16x8 __attribute__((ext_vector_type(8)));

__device__ __forceinline__ unsigned short f2bf(float f) {
    union { float f; unsigned int i; } c; c.f = f;
    unsigned int u = c.i;
    u += 0x7fffu + ((u >> 16) & 1u);   // round-to-nearest-even
    return (unsigned short)(u >> 16);
}
__device__ __forceinline__ float sigm(float x) { return 1.f / (1.f + __expf(-x)); }

// async global->LDS DMA, 16B/lane (GEMM staging only)
__device__ __forceinline__ void dma16(const void* g, void* l) {
    __builtin_amdgcn_global_load_lds(
        (const __attribute__((address_space(1))) void*)g,
        (__attribute__((address_space(3))) void*)l, 16, 0, 0);
}

// DPP row_ror butterfly (k_prep / k_bg only)
template <int CTRL>
__device__ __forceinline__ float dppadd(float x) {
    int v = __builtin_amdgcn_update_dpp(0, __builtin_bit_cast(int, x), CTRL, 0xf, 0xf, false);
    return x + __builtin_bit_cast(float, v);
}
__device__ __forceinline__ float rowsum16(float x) {
    x = dppadd<0x128>(x);
    x = dppadd<0x124>(x);
    x = dppadd<0x122>(x);
    x = dppadd<0x121>(x);
    return x;
}

// ---------------------------------------------------------------- LayerNorm
__global__ __launch_bounds__(256, 1) void k_ln(const float* __restrict__ x,
                                               const float* __restrict__ lnw,
                                               const float* __restrict__ lnb,
                                               unsigned short* __restrict__ xn) {
    const int m = blockIdx.x;
    const int t = threadIdx.x;
    float4 xv = ((const float4*)(x + (size_t)m * DMODEL))[t];
    float s = xv.x + xv.y + xv.z + xv.w;
    float s2 = xv.x * xv.x + xv.y * xv.y + xv.z * xv.z + xv.w * xv.w;
#pragma unroll
    for (int off = 32; off >= 1; off >>= 1) {
        s += __shfl_xor(s, off);
        s2 += __shfl_xor(s2, off);
    }
    __shared__ float red[8];
    const int wid = t >> 6;
    if ((t & 63) == 0) { red[wid] = s; red[4 + wid] = s2; }
    __syncthreads();
    if (t == 0) {
        float su = red[0] + red[1] + red[2] + red[3];
        float sq = red[4] + red[5] + red[6] + red[7];
        float mu = su * (1.f / DMODEL);
        float var = sq * (1.f / DMODEL) - mu * mu;
        red[0] = mu;
        red[1] = rsqrtf(var + 1e-5f);
    }
    __syncthreads();
    float mu = red[0], rstd = red[1];
    float4 w4 = ((const float4*)lnw)[t];
    float4 b4 = ((const float4*)lnb)[t];
    ushort4 o;
    o.x = f2bf((xv.x - mu) * rstd * w4.x + b4.x);
    o.y = f2bf((xv.y - mu) * rstd * w4.y + b4.y);
    o.z = f2bf((xv.z - mu) * rstd * w4.z + b4.z);
    o.w = f2bf((xv.w - mu) * rstd * w4.w + b4.w);
    ((ushort4*)(xn + (size_t)m * DMODEL))[t] = o;
}

// ------------------------------------------- fp32 -> bf16 weight conversion
struct WPtrs { const float* p0; const float* p1; const float* p2; const float* p3; const float* p4; };

__global__ __launch_bounds__(256, 1) void k_wconv(WPtrs w, unsigned short* __restrict__ dst) {
    const int plane = blockIdx.y;
    const float* src = plane == 0 ? w.p0 : plane == 1 ? w.p1 : plane == 2 ? w.p2
                                                             : plane == 3 ? w.p3 : w.p4;
    const size_t i = ((size_t)blockIdx.x * 256 + threadIdx.x) * 8;
    float4 f0 = *(const float4*)(src + i);
    float4 f1 = *(const float4*)(src + i + 4);
    uint4 o;
    o.x = (unsigned)f2bf(f0.x) | ((unsigned)f2bf(f0.y) << 16);
    o.y = (unsigned)f2bf(f0.z) | ((unsigned)f2bf(f0.w) << 16);
    o.z = (unsigned)f2bf(f1.x) | ((unsigned)f2bf(f1.y) << 16);
    o.w = (unsigned)f2bf(f1.z) | ((unsigned)f2bf(f1.w) << 16);
    *(uint4*)(dst + (size_t)plane * 1048576 + i) = o;
}

__global__ __launch_bounds__(256, 1) void k_cvt1(const float* __restrict__ src,
                                                 unsigned short* __restrict__ dst) {
    const size_t i = ((size_t)blockIdx.x * 256 + threadIdx.x) * 8;
    float4 f0 = *(const float4*)(src + i);
    float4 f1 = *(const float4*)(src + i + 4);
    uint4 o;
    o.x = (unsigned)f2bf(f0.x) | ((unsigned)f2bf(f0.y) << 16);
    o.y = (unsigned)f2bf(f0.z) | ((unsigned)f2bf(f0.w) << 16);
    o.z = (unsigned)f2bf(f1.x) | ((unsigned)f2bf(f1.y) << 16);
    o.w = (unsigned)f2bf(f1.z) | ((unsigned)f2bf(f1.w) << 16);
    *(uint4*)(dst + i) = o;
}

// ------------------------------------------------- 128x128 bf16 MFMA tile GEMM
template <int KDIM>
__device__ __forceinline__ void gemm128(const unsigned short* __restrict__ A,
                                        const unsigned short* __restrict__ Bw,
                                        int m0, int n0, f32x4 acc[4][4]) {
    __shared__ __align__(16) unsigned short sA[128 * 32];
    __shared__ __align__(16) unsigned short sB[128 * 32];

    const int t = threadIdx.x;
    const int lane = t & 63;
    const int wv = t >> 6;
    const int wm = wv >> 1, wn = wv & 1;
    const int ml = lane & 15, kq = lane >> 4;

#pragma unroll
    for (int i = 0; i < 4; i++)
#pragma unroll
        for (int j = 0; j < 4; j++) {
            f32x4 z; z[0] = 0.f; z[1] = 0.f; z[2] = 0.f; z[3] = 0.f;
            acc[i][j] = z;
        }

    const unsigned short* pA = A + (size_t)m0 * KDIM;
    const unsigned short* pB = Bw + (size_t)n0 * KDIM;
    const unsigned short* gA0 = pA + (size_t)(t >> 2) * KDIM + (t & 3) * 8;
    const unsigned short* gA1 = gA0 + (size_t)64 * KDIM;
    const unsigned short* gB0 = pB + (size_t)(t >> 2) * KDIM + (t & 3) * 8;
    const unsigned short* gB1 = gB0 + (size_t)64 * KDIM;
    unsigned short* lA0 = sA + wv * 512;
    unsigned short* lA1 = lA0 + 2048;
    unsigned short* lB0 = sB + wv * 512;
    unsigned short* lB1 = lB0 + 2048;

    for (int kb = 0; kb < KDIM / 32; kb++) {
        const int ko = kb * 32;
        dma16(gA0 + ko, lA0);
        dma16(gA1 + ko, lA1);
        dma16(gB0 + ko, lB0);
        dma16(gB1 + ko, lB1);
        __syncthreads();
        bf16x8 af[4], bfr[4];
#pragma unroll
        for (int mt = 0; mt < 4; mt++)
            af[mt] = *(const bf16x8*)&sA[(wm * 64 + mt * 16 + ml) * 32 + kq * 8];
#pragma unroll
        for (int nt = 0; nt < 4; nt++)
            bfr[nt] = *(const bf16x8*)&sB[(wn * 64 + nt * 16 + ml) * 32 + kq * 8];
#pragma unroll
        for (int mt = 0; mt < 4; mt++)
#pragma unroll
            for (int nt = 0; nt < 4; nt++)
                acc[mt][nt] = __builtin_amdgcn_mfma_f32_16x16x32_bf16(af[mt], bfr[nt], acc[mt][nt], 0, 0, 0);
        __syncthreads();
    }
}

// -------------------------------------------- fused 5-way projection GEMM
__global__ __launch_bounds__(256, 1) void k_proj(const unsigned short* __restrict__ xn,
                                                 const unsigned short* __restrict__ wbf,
                                                 const float* __restrict__ ba,
                                                 const float* __restrict__ baR,
                                                 __half* __restrict__ qo, __half* __restrict__ ko,
                                                 __half* __restrict__ vo, __half* __restrict__ ao,
                                                 __half* __restrict__ aRo) {
    const int m0 = blockIdx.x * 128;
    const int yt = blockIdx.y;
    const int widx = yt >> 3;
    const int n0 = (yt & 7) * 128;
    const unsigned short* W = wbf + (size_t)widx * 1048576;
    f32x4 acc[4][4];
    gemm128<1024>(xn, W, m0, n0, acc);

    __half* outp = widx == 0 ? qo : widx == 1 ? ko : widx == 2 ? vo : widx == 3 ? ao : aRo;
    const float* bias = (widx == 3) ? ba : (widx == 4) ? baR : (const float*)0;
    const int lane = threadIdx.x & 63;
    const int wv = threadIdx.x >> 6;
    const int wm = wv >> 1, wn = wv & 1;
    const int ml = lane & 15, kq = lane >> 4;
#pragma unroll
    for (int mt = 0; mt < 4; mt++)
#pragma unroll
        for (int nt = 0; nt < 4; nt++) {
            const int rowg = m0 + wm * 64 + mt * 16 + kq * 4;
            const int colg = n0 + wn * 64 + nt * 16 + ml;
            float bval = bias ? bias[colg] : 0.f;
#pragma unroll
            for (int r = 0; r < 4; r++) {
                float v = acc[mt][nt][r];
                if (widx >= 3) v = sigm(v + bval);
                outp[(size_t)(rowg + r) * DMODEL + colg] = __float2half(v);
            }
        }
}

// --------------------------------------------------- beta/gamma skinny GEMM
__global__ __launch_bounds__(256, 1) void k_bg(const unsigned short* __restrict__ xn,
                                               const float* __restrict__ Wb,
                                               const float* __restrict__ bb,
                                               const float* __restrict__ Wg,
                                               const float* __restrict__ bgp,
                                               f32x2* __restrict__ bgpk) {
    const int m = blockIdx.x;
    const int t = threadIdx.x;
    const int h = t >> 4, seg = t & 15;
    const ushort4* xr = (const ushort4*)(xn + (size_t)m * DMODEL + seg * 64);
    const float4* wbr = (const float4*)(Wb + (size_t)h * DMODEL + seg * 64);
    const float4* wgr = (const float4*)(Wg + (size_t)h * DMODEL + seg * 64);
    float db = 0.f, dg = 0.f;
#pragma unroll
    for (int u = 0; u < 16; u++) {
        ushort4 a = xr[u];
        float4 w1 = wbr[u], w2 = wgr[u];
        union { unsigned int i; float f; } c0, c1, c2, c3;
        c0.i = ((unsigned int)a.x) << 16; c1.i = ((unsigned int)a.y) << 16;
        c2.i = ((unsigned int)a.z) << 16; c3.i = ((unsigned int)a.w) << 16;
        db += c0.f * w1.x + c1.f * w1.y + c2.f * w1.z + c3.f * w1.w;
        dg += c0.f * w2.x + c1.f * w2.y + c2.f * w2.z + c3.f * w2.w;
    }
#pragma unroll
    for (int off = 1; off < 16; off <<= 1) {
        db += __shfl_xor(db, off);
        dg += __shfl_xor(dg, off);
    }
    if (seg == 0) {
        f32x2 o;
        o[0] = sigm(db + bb[h]);
        o[1] = sigm(dg + bgp[h]);
        bgpk[(size_t)m * NH + h] = o;
    }
}

// ------------------------------------------- k normalization (in-place, fp16)
__global__ __launch_bounds__(256, 1) void k_prep(__half* __restrict__ kb) {
    const int row = blockIdx.x * 16 + (threadIdx.x >> 4);
    const int tr = threadIdx.x & 15;
    const int bh = row >> 11, t = row & 2047;
    const size_t idx = ((size_t)((bh >> 4) * T_SEQ + t)) * DMODEL + (bh & 15) * 64 + tr * 4;
    f16x4 k4 = *(const f16x4*)((const __half*)kb + idx);
    float k0 = (float)k4[0], k1 = (float)k4[1], k2 = (float)k4[2], k3 = (float)k4[3];
    float ss = k0 * k0 + k1 * k1 + k2 * k2 + k3 * k3;
    ss = rowsum16(ss);
    float inv = 1.f / fmaxf(sqrtf(ss), 1e-12f);
    f16x4 o;
    o[0] = (_Float16)(k0 * inv); o[1] = (_Float16)(k1 * inv);
    o[2] = (_Float16)(k2 * inv); o[3] = (_Float16)(k3 * inv);
    *(f16x4*)(kb + idx) = o;
}

// ------------------------------------------------------------- the scan (MFMA)
// 256 blocks x 1 wave (64 thr). blk&63 = bh (XCD co-location), blk>>6 = cg.
// State of 16 columns lives in MFMA B-fragment layout (fp16):
//   S[k][n]: lane holds n=lane&15, k = quad*8+i (two frags for K=64).
// kn/q in A-fragment layout with rows replicated (lane value depends only on
// quad -> plain 16B load replicates). pred/kp/kpR/o = 2 independent
// mfma_f32_16x16x32_f16 each; A-row replication makes every lane's acc[0] the
// per-column scalar -> NO cross-lane reductions at all.
__global__ __launch_bounds__(64, 1) void k_scan(const __half* __restrict__ qb,
                                                const __half* __restrict__ knb,
                                                const __half* __restrict__ vb,
                                                const __half* __restrict__ ab,
                                                const __half* __restrict__ aRb,
                                                const f32x2* __restrict__ bgpk,
                                                unsigned short* __restrict__ ob) {
    const int blk = blockIdx.x;
    const int bh = blk & 63, cg = blk >> 6;   // XCD co-location swizzle
    const int b = bh >> 4, h = bh & 15;
    const int l = threadIdx.x;
    const int col = l & 15, quad = l >> 4;
    const int ii = cg * 16 + col;

    const size_t base = (size_t)b * T_SEQ * DMODEL + h * 64;
    const __half* pk = knb + base + quad * 8;
    const __half* pq = qb + base + quad * 8;
    const __half* pa = ab + base + quad * 8;
    const __half* pr = aRb + base + quad * 8;
    const __half* pv = vb + base + ii;
    unsigned short* po = ob + base + ii;
    const size_t bgbase = (size_t)b * T_SEQ * NH + h;

    f16x8 SL = (f16x8)(_Float16)0, SH = (f16x8)(_Float16)0;
    f16x8 RL = (f16x8)(_Float16)0, RH = (f16x8)(_Float16)0;

    struct In {
        f16x8 knL, knH, aL, aH, xL, xH, qL, qH;
        float vc;
        f32x2 bg;
    };

    auto load = [&](int s) {
        In r;
        const size_t vo = (size_t)s * DMODEL;
        r.knL = *(const f16x8*)(pk + vo); r.knH = *(const f16x8*)(pk + vo + 32);
        r.aL = *(const f16x8*)(pa + vo);  r.aH = *(const f16x8*)(pa + vo + 32);
        r.xL = *(const f16x8*)(pr + vo);  r.xH = *(const f16x8*)(pr + vo + 32);
        r.qL = *(const f16x8*)(pq + vo);  r.qH = *(const f16x8*)(pq + vo + 32);
        r.vc = (float)pv[vo];
        r.bg = bgpk[bgbase + (size_t)s * NH];
        return r;
    };

    auto step = [&](const In& c, int s) {
        // pred = kn . S  (old state)
        f32x4 z; z[0] = 0.f; z[1] = 0.f; z[2] = 0.f; z[3] = 0.f;
        f32x4 pA1 = __builtin_amdgcn_mfma_f32_16x16x32_f16(c.knL, SL, z, 0, 0, 0);
        f32x4 pA2 = __builtin_amdgcn_mfma_f32_16x16x32_f16(c.knH, SH, z, 0, 0, 0);
        // decayed states
        f16x8 SdL = c.aL * SL, SdH = c.aH * SH;
        f16x8 RdL = c.xL * RL, RdH = c.xH * RH;
        // kp = kn . Sd ; kpR = kn . Rd
        f32x4 kA1 = __builtin_amdgcn_mfma_f32_16x16x32_f16(c.knL, SdL, z, 0, 0, 0);
        f32x4 kA2 = __builtin_amdgcn_mfma_f32_16x16x32_f16(c.knH, SdH, z, 0, 0, 0);
        f32x4 rA1 = __builtin_amdgcn_mfma_f32_16x16x32_f16(c.knL, RdL, z, 0, 0, 0);
        f32x4 rA2 = __builtin_amdgcn_mfma_f32_16x16x32_f16(c.knH, RdH, z, 0, 0, 0);
        const float pred = pA1[0] + pA2[0];
        const float kp = kA1[0] + kA2[0];
        const float kpR = rA1[0] + rA2[0];
        const float rres = fminf(fmaxf(c.vc - pred, -1.f), 1.f);
        const float cS = c.bg[0] * (c.vc - kp);
        const float cR = c.bg[1] * (rres - kpR);
        const _Float16 csh = (_Float16)cS;
        const _Float16 crh = (_Float16)cR;
        const f16x8 csv = {csh, csh, csh, csh, csh, csh, csh, csh};
        const f16x8 crv = {crh, crh, crh, crh, crh, crh, crh, crh};
        SL = SdL + csv * c.knL; SH = SdH + csv * c.knH;
        RL = RdL + crv * c.knL; RH = RdH + crv * c.knH;
        // o = q . (S + R)
        f16x8 TL = SL + RL, TH = SH + RH;
        f32x4 oA1 = __builtin_amdgcn_mfma_f32_16x16x32_f16(c.qL, TL, z, 0, 0, 0);
        f32x4 oA2 = __builtin_amdgcn_mfma_f32_16x16x32_f16(c.qH, TH, z, 0, 0, 0);
        if (quad == 0)
            po[(size_t)s * DMODEL] = f2bf(oA1[0] + oA2[0]);
    };

    In bufA = load(0), bufB;
    for (int s = 0; s < T_SEQ; s += 2) {
        bufB = load((s + 1) & (T_SEQ - 1));
        step(bufA, s);
        bufA = load((s + 2) & (T_SEQ - 1));
        step(bufB, s + 1);
    }
}

// ---------------------------------------------------- output GEMM + residual
__global__ __launch_bounds__(256, 1) void k_out(const unsigned short* __restrict__ ob,
                                                const unsigned short* __restrict__ wobf,
                                                const float* __restrict__ x,
                                                float* __restrict__ out) {
    const int m0 = blockIdx.x * 128;
    const int n0 = blockIdx.y * 128;
    f32x4 acc[4][4];
    gemm128<1024>(ob, wobf, m0, n0, acc);
    const int lane = threadIdx.x & 63;
    const int wv = threadIdx.x >> 6;
    const int wm = wv >> 1, wn = wv & 1;
    const int ml = lane & 15, kq = lane >> 4;
#pragma unroll
    for (int mt = 0; mt < 4; mt++)
#pragma unroll
        for (int nt = 0; nt < 4; nt++) {
            const int rowg = m0 + wm * 64 + mt * 16 + kq * 4;
            const int colg = n0 + wn * 64 + nt * 16 + ml;
#pragma unroll
            for (int r = 0; r < 4; r++) {
                size_t idx = (size_t)(rowg + r) * DMODEL + colg;
                out[idx] = acc[mt][nt][r] + x[idx];
            }
        }
}

extern "C" void kernel_launch(void* const* d_in, const int* in_sizes, int n_in,
                              void* d_out, int out_size, void* d_ws, size_t ws_size,
                              hipStream_t stream) {
    const float* x = (const float*)d_in[0];
    const float* Wq = (const float*)d_in[1];
    const float* Wk = (const float*)d_in[2];
    const float* Wv = (const float*)d_in[3];
    const float* Wa = (const float*)d_in[4];
    const float* ba = (const float*)d_in[5];
    const float* Wb = (const float*)d_in[6];
    const float* bb = (const float*)d_in[7];
    const float* Wg = (const float*)d_in[8];
    const float* bg = (const float*)d_in[9];
    const float* WaR = (const float*)d_in[10];
    const float* baR = (const float*)d_in[11];
    const float* Wo = (const float*)d_in[12];
    const float* lnw = (const float*)d_in[13];
    const float* lnb = (const float*)d_in[14];

    const size_t SZ = 16777216ULL;  // one fp16/bf16 plane (8192*1024*2 B)
    size_t need = 6 * SZ + 2 * 1048576ULL;
    if (ws_size < need) return;

    char* ws = (char*)d_ws;
    __half* qb = (__half*)(ws + 0 * SZ);
    __half* kb = (__half*)(ws + 1 * SZ);
    __half* vb = (__half*)(ws + 2 * SZ);
    __half* ab = (__half*)(ws + 3 * SZ);
    __half* aRb = (__half*)(ws + 4 * SZ);
    unsigned short* xn = (unsigned short*)(ws + 5 * SZ);  // bf16; reused for o
    f32x2* bgpk = (f32x2*)(ws + 6 * SZ);                   // 1 MB (+1 MB slack)

    // d_out doubles as scratch for bf16 projection weights (10 MB of 32 MB);
    // only read by k_proj, fully overwritten by k_out at the end.
    unsigned short* wbf = (unsigned short*)d_out;
    // Wo-bf16 goes into the (dead after scan) qb plane.
    unsigned short* wobf = (unsigned short*)qb;

    WPtrs wp{Wq, Wk, Wv, Wa, WaR};
    k_wconv<<<dim3(512, 5), dim3(256), 0, stream>>>(wp, wbf);
    k_ln<<<dim3(MTOT), dim3(256), 0, stream>>>(x, lnw, lnb, xn);
    k_proj<<<dim3(64, 40), dim3(256), 0, stream>>>(xn, wbf, ba, baR, qb, kb, vb, ab, aRb);
    k_bg<<<dim3(MTOT), dim3(256), 0, stream>>>(xn, Wb, bb, Wg, bg, bgpk);
    k_prep<<<dim3(MTOT * NH / 16), dim3(256), 0, stream>>>(kb);  // kb -> kn in place
    // scan writes o (bf16) over xn (xn dead after k_proj/k_bg)
    k_scan<<<dim3(256), dim3(64), 0, stream>>>(qb, kb, vb, ab, aRb, bgpk, xn);
    k_cvt1<<<dim3(512), dim3(256), 0, stream>>>(Wo, wobf);  // qb dead after scan
    k_out<<<dim3(64, 8), dim3(256), 0, stream>>>(xn, wobf, x, (float*)d_out);
}